// Round 9
// baseline (2473.702 us; speedup 1.0000x reference)
//
#include <hip/hip_runtime.h>
#include <stdint.h>

typedef unsigned short u16;
typedef unsigned long long u64;
typedef short short8 __attribute__((ext_vector_type(8)));
typedef unsigned short u16x4 __attribute__((ext_vector_type(4)));
typedef unsigned short u16x8 __attribute__((ext_vector_type(8)));
typedef float f32x4 __attribute__((ext_vector_type(4)));

#define MFMA16x16x32 __builtin_amdgcn_mfma_f32_16x16x32_bf16

#define TSLOT   49152L     // u16 per h/x time-slot (64 x 768)
#define XPSLOT  98304L     // u16 per Xp time-slot per kidx (64 x 1536)

// ws byte layout: flags | Xstage(200) | Xp0 | Xp1 | l0h(201) | l1h(201)
// Xp0/Xp1 are 200-slot histories if ws_size allows (big mode: cached reads),
// else 32-slot rings (R8 behavior: sc1 reads + back-pressure).
#define WS_FLAGS 256L
#define WS_XSTG  16640L
#define WS_XP0   (WS_XSTG + 200L*TSLOT*2)
#define BIG_TOTAL 216482048L

static __device__ __forceinline__ float bf2f(u16 u){
  union{unsigned int i; float f;} v; v.i=((unsigned int)u)<<16; return v.f;
}
static __device__ __forceinline__ u16 f2bf(float f){
  union{float f; unsigned int i;} v; v.f=f;
  return (u16)((v.i + 0x7fffu + ((v.i>>16)&1u))>>16);   // RNE
}
static __device__ __forceinline__ float sigf(float x){
  return __fdividef(1.f, 1.f + __expf(-x));
}
static __device__ __forceinline__ float tanh_(float x){
  return 1.f - __fdividef(2.f, __expf(2.f*x) + 1.f);
}
// coherent (agent-scope, LLC-direct): h/Xp stores, ring-mode reads, flags
static __device__ __forceinline__ u64 cohld(const u16* p){
  return __hip_atomic_load((const u64*)p, __ATOMIC_RELAXED, __HIP_MEMORY_SCOPE_AGENT);
}
static __device__ __forceinline__ void cohst(u16* p, u64 v){
  __hip_atomic_store((u64*)p, v, __ATOMIC_RELAXED, __HIP_MEMORY_SCOPE_AGENT);
}
static __device__ __forceinline__ int fld(const int* flags, int fi){
  return __hip_atomic_load(&flags[fi*32], __ATOMIC_RELAXED, __HIP_MEMORY_SCOPE_AGENT);
}
static __device__ __forceinline__ void fst(int* flags, int fi, int v){
  __hip_atomic_store(&flags[fi*32], v, __ATOMIC_RELAXED, __HIP_MEMORY_SCOPE_AGENT);
}
// mode: 1 = tensor is fp32 (convert on load), 0 = tensor is bf16
static __device__ __forceinline__ short8 ldw8(const void* base, long e, int mode){
  if (mode==0) return *(const short8*)((const u16*)base + e);
  const float* p = (const float*)base + e;
  float4 a = *(const float4*)p, b = *(const float4*)(p+4);
  short8 r; r[0]=(short)f2bf(a.x); r[1]=(short)f2bf(a.y); r[2]=(short)f2bf(a.z); r[3]=(short)f2bf(a.w);
  r[4]=(short)f2bf(b.x); r[5]=(short)f2bf(b.y); r[6]=(short)f2bf(b.z); r[7]=(short)f2bf(b.w);
  return r;
}
static __device__ __forceinline__ float lds1(const void* base, long e, int mode){
  return mode ? ((const float*)base)[e] : bf2f(((const u16*)base)[e]);
}

// ---- Kd: dtype detection on raw W_emb words (fp32 vs bf16) -----------------
__global__ void kdet(const unsigned int* __restrict__ w, int* wsmode){
  __shared__ int sh[256];
  int c = 0;
  for (int i=threadIdx.x; i<4096; i+=256){
    unsigned int x = w[i] & 0xFFFFu;
    if (((x>>7)&0xFFu) >= 0x80u) c++;
  }
  sh[threadIdx.x]=c; __syncthreads();
  for (int s=128;s>0;s>>=1){
    if (threadIdx.x<s) sh[threadIdx.x]+=sh[threadIdx.x+s];
    __syncthreads();
  }
  if (threadIdx.x==0) wsmode[0] = (sh[0] > 256) ? 1 : 0;
}

// ---- K0: zero h slot-0s + flags --------------------------------------------
__global__ void k0_init(unsigned int* l0h, unsigned int* l1h, int* flags){
  int i = blockIdx.x*256 + threadIdx.x;       // 96*256 = 24576
  l0h[i] = 0u;
  l1h[i] = 0u;
  if (i < 4096) flags[i] = 0;                 // 128 flags, 128B-strided
}

// ---- Kx: Xstage[t][b][0:768] = emb[ctx[b][t]] as bf16 (gather ONCE) --------
__global__ __launch_bounds__(256) void kx(
    const void* __restrict__ emb, const int* __restrict__ ctx,
    const int* __restrict__ wsmode, u16* __restrict__ xstg){
  const int mode = wsmode[0];
  long f = ((long)blockIdx.x*256 + threadIdx.x)*8;   // u16 flat index
  long row = f / 768;  int col = (int)(f % 768);
  int t = (int)(row >> 6), b = (int)(row & 63);
  long token = ctx[b*200 + t];
  if (mode){
    const float* p = (const float*)emb + token*768 + col;
    float4 a = *(const float4*)p, bb = *(const float4*)(p+4);
    u16x8 v; v[0]=f2bf(a.x); v[1]=f2bf(a.y); v[2]=f2bf(a.z); v[3]=f2bf(a.w);
    v[4]=f2bf(bb.x); v[5]=f2bf(bb.y); v[6]=f2bf(bb.z); v[7]=f2bf(bb.w);
    *(u16x8*)(xstg + f) = v;
  } else {
    *(u16x8*)(xstg + f) = *(const u16x8*)((const u16*)emb + token*768 + col);
  }
}

// ---- K3: 128 persistent WGs -------------------------------------------------
// wg 0..15  l0 chains (d=wg>>3, slot=wg&7): 48 hdims; K=384 recurrence.
// wg 16..31 l1 chains.
// wg 32..79 Xp0 producers (phase-split t&1, 12 slices x 32 hdims).
// wg 80..127 Xp1 producers.
// big mode: Xp is a 200-slot write-once history => chains read it CACHED
// (sc1-write + flag + cached-first-touch-read pattern, validated R8); no
// ring back-pressure; Xp0 producers free-run off the critical path.
// ring mode (small ws): exact R8 behavior (sc1 slice reads, 32-ring).
__global__ __launch_bounds__(256,1) void k3_lstm(
    const void* __restrict__ wih, const void* __restrict__ whh,
    const void* __restrict__ blstm, const int* __restrict__ pos,
    const u16* __restrict__ xstg, u16* __restrict__ xp0, u16* __restrict__ xp1,
    u16* __restrict__ l0h, u16* __restrict__ l1h,
    int* flags, const int* __restrict__ wsmode, float* __restrict__ out,
    int big, int xmask, int dslots){
  __shared__ __align__(16) u16 lact[64*776];
  __shared__ __align__(16) u16 hstage[64*48];
  __shared__ int spos[64];
  const int mode = wsmode[0];
  const int tid = threadIdx.x, lane = tid & 63, w = tid >> 6;
  const int m15 = lane & 15, q = lane >> 4;
  const int g = m15 & 3, hl = m15 >> 2;        // A-row m15 -> (gate, hdim)
  const int wg = blockIdx.x;

  if (wg < 32){
    // ================= chain WG =================
    const int layer = wg >> 4, x = wg & 15, d = x >> 3, slot = x & 7;
    const int kidx = 2*layer + d;
    const int j0 = slot*48 + w*12;             // 12 hdims (3 Mtiles)
    const void* whhd = mode ? (const void*)((const float*)whh + (long)kidx*1536*384)
                            : (const void*)((const u16*)whh + (long)kidx*1536*384);
    short8 wa[3][12];
#pragma unroll
    for (int Mt=0;Mt<3;Mt++){
      long row = (long)g*384 + j0 + Mt*4 + hl;
#pragma unroll
      for (int ks=0;ks<12;ks++)
        wa[Mt][ks] = ldw8(whhd, row*384 + ks*32 + q*8, mode);
    }
    if (tid < 64) spos[tid] = pos[tid];
    u16* xpk  = (layer ? xp1 : xp0) + (long)d*dslots*XPSLOT;
    u16* hbuf = layer ? l1h : l0h;
    const int selfF = wg;
    const int peerB = layer*16 + d*8;
    const int prodB = (layer ? 80 : 32) + d*24;
    float cst[3][4];
#pragma unroll
    for(int i=0;i<3;i++)
#pragma unroll
      for(int j=0;j<4;j++) cst[i][j]=0.f;

    for (int t=0;t<200;++t){
      if (w==0){
        int fi, tgt;
        if (lane < 8){ fi = peerB + lane; tgt = t; }                   // peers: h[t]
        else if (lane < 20){ fi = prodB + (t&1)*12 + (lane-8); tgt = t+1; } // Xp[t]
        else { fi = 0; tgt = 0; }
        while (1){ int v = fld(flags, fi); if (__all(v >= tgt)) break;
                   __builtin_amdgcn_s_sleep(1); }
      }
      __syncthreads();
      // acc-init from Xp[t]: cached u16x4 in big mode (write-once history),
      // coherent 8B in ring mode
      u16x4 xr[3][4];
      const long xb = (long)(t & xmask)*XPSLOT;
      if (big){
#pragma unroll
        for (int Mt=0;Mt<3;Mt++)
#pragma unroll
          for (int Nt=0;Nt<4;Nt++)
            xr[Mt][Nt] = *(const u16x4*)(xpk + xb + (long)(Nt*16+m15)*1536 + (j0+Mt*4+q)*4);
      } else {
#pragma unroll
        for (int Mt=0;Mt<3;Mt++)
#pragma unroll
          for (int Nt=0;Nt<4;Nt++){
            union{u64 v; u16x4 h;} u;
            u.v = cohld(xpk + xb + (long)(Nt*16+m15)*1536 + (j0+Mt*4+q)*4);
            xr[Mt][Nt] = u.h;
          }
      }
      // stage own-dir h[t]: 64x384 bf16, CACHED 16B (write-once history)
      {
        const long hb = (long)t*TSLOT;
#pragma unroll
        for (int r=0;r<12;r++){
          int flat = r*4096 + tid*16;          // byte offset within 64x768B
          int rowi = flat/768, off = (flat%768)>>1;
          *(u16x8*)&lact[rowi*392+off] =
            *(const u16x8*)(hbuf + hb + (long)rowi*768 + d*384 + off);
        }
      }
      __syncthreads();
      f32x4 acc[3][4];
#pragma unroll
      for (int Mt=0;Mt<3;Mt++)
#pragma unroll
        for (int Nt=0;Nt<4;Nt++)
          acc[Mt][Nt] = (f32x4){ bf2f(xr[Mt][Nt][0]), bf2f(xr[Mt][Nt][1]),
                                 bf2f(xr[Mt][Nt][2]), bf2f(xr[Mt][Nt][3]) };
#pragma unroll
      for (int ks=0;ks<12;ks++){
        short8 bf[4];
#pragma unroll
        for (int Nt=0;Nt<4;Nt++)
          bf[Nt] = *(const short8*)&lact[(Nt*16 + m15)*392 + ks*32 + q*8];
#pragma unroll
        for (int Mt=0;Mt<3;Mt++)
#pragma unroll
          for (int Nt=0;Nt<4;Nt++)
            acc[Mt][Nt] = MFMA16x16x32(wa[Mt][ks], bf[Nt], acc[Mt][Nt], 0,0,0);
      }
#pragma unroll
      for (int Mt=0;Mt<3;Mt++)
#pragma unroll
        for (int Nt=0;Nt<4;Nt++){
          float gi = sigf(acc[Mt][Nt][0]);     // bias folded into Xp
          float gf = sigf(acc[Mt][Nt][1]);
          float gz = tanh_(acc[Mt][Nt][2]);
          float go = sigf(acc[Mt][Nt][3]);
          float c2 = gf*cst[Mt][Nt] + gi*gz;   // c stays fp32 in registers
          cst[Mt][Nt] = c2;
          float hn = go*tanh_(c2);
          hstage[(Nt*16 + m15)*48 + (w*12 + Mt*4 + q)] = f2bf(hn);
          if (layer==1 && spos[Nt*16 + m15] == t)
            out[256 + (Nt*16 + m15)*768 + d*384 + slot*48 + w*12 + Mt*4 + q] = hn;
        }
      __syncthreads();
      {                                        // h[t+1] write-through: 64x48 bf16
        const long ob = (long)(t+1)*TSLOT;
#pragma unroll
        for (int s2=0;s2<3;s2++){
          int flat = tid*24 + s2*8;
          int b = flat/96, off = (flat%96)>>1;
          cohst(hbuf + ob + (long)b*768 + d*384 + slot*48 + off,
                *(const u64*)&hstage[b*48 + off]);
        }
      }
      __syncthreads();                         // vmcnt drain: release order
      if (tid==0) fst(flags, selfF, t+1);
    }
  } else {
    // ================= Xp producer WG =================
    const int isl1 = (wg >= 80);
    const int pidx = wg - (isl1 ? 80 : 32);
    const int d = pidx / 24, r24 = pidx % 24;
    const int phase = r24 / 12, slice = r24 % 12;
    const int kidx = isl1 ? 2 + d : d;
    const int j0h = slice*32 + w*8;            // 8 hdims (2 Mtiles)
    const void* wihd = mode ? (const void*)((const float*)wih + (long)kidx*1536*768)
                            : (const void*)((const u16*)wih + (long)kidx*1536*768);
    short8 wbh[2][24];
#pragma unroll
    for (int Mt=0;Mt<2;Mt++){
      long row = (long)g*384 + j0h + Mt*4 + hl;
#pragma unroll
      for (int ks=0;ks<24;ks++)
        wbh[Mt][ks] = ldw8(wihd, row*768 + ks*32 + q*8, mode);
    }
    float bias[2][4];
#pragma unroll
    for (int Mt=0;Mt<2;Mt++)
#pragma unroll
      for (int r=0;r<4;r++)
        bias[Mt][r] = lds1(blstm, (long)kidx*1536 + r*384 + j0h + Mt*4 + q, mode);
    u16* xpk = (isl1 ? xp1 : xp0) + (long)d*dslots*XPSLOT;
    const int selfF = wg;
    const int chainB = isl1 ? 16 + d*8 : d*8;

    for (int t=phase; t<200; t+=2){
      if (w==0){
        int fi = 0, tgt = 0;
        if (!big && lane < 8){ fi = chainB + lane; tgt = t - 31; }     // ring space
        if (isl1 && lane >= 8 && lane < 24){ fi = lane - 8; tgt = t+1; } // l0h[t+1]
        while (1){ int v = fld(flags, fi); if (__all(v >= tgt)) break;
                   __builtin_amdgcn_s_sleep(1); }
      }
      __syncthreads();
      // stage input 64x768 bf16: CACHED 16B (Xstage or l0h history)
      {
        const u16* src = isl1 ? (l0h + (long)(t+1)*TSLOT) : (xstg + (long)t*TSLOT);
#pragma unroll
        for (int r=0;r<24;r++){
          int e = r*2048 + tid*8;              // u16 element index
          int rowi = e/768, off = e%768;
          *(u16x8*)&lact[rowi*776 + off] = *(const u16x8*)(src + (long)rowi*768 + off);
        }
      }
      __syncthreads();
      f32x4 acc[2][4];
#pragma unroll
      for (int Mt=0;Mt<2;Mt++)
#pragma unroll
        for (int Nt=0;Nt<4;Nt++) acc[Mt][Nt] = (f32x4){0.f,0.f,0.f,0.f};
#pragma unroll
      for (int ks=0;ks<24;ks++){
        short8 bf[4];
#pragma unroll
        for (int Nt=0;Nt<4;Nt++)
          bf[Nt] = *(const short8*)&lact[(Nt*16 + m15)*776 + ks*32 + q*8];
#pragma unroll
        for (int Mt=0;Mt<2;Mt++)
#pragma unroll
          for (int Nt=0;Nt<4;Nt++)
            acc[Mt][Nt] = MFMA16x16x32(wbh[Mt][ks], bf[Nt], acc[Mt][Nt], 0,0,0);
      }
      {                                        // Xp[t] slices: coherent 8B stores
        const long xb = (long)(t & xmask)*XPSLOT;
#pragma unroll
        for (int Mt=0;Mt<2;Mt++)
#pragma unroll
          for (int Nt=0;Nt<4;Nt++){
            union{u64 v; u16x4 h;} u;
#pragma unroll
            for (int r=0;r<4;r++) u.h[r] = f2bf(acc[Mt][Nt][r] + bias[Mt][r]);
            cohst(xpk + xb + (long)(Nt*16+m15)*1536 + (j0h + Mt*4 + q)*4, u.v);
          }
      }
      __syncthreads();                         // vmcnt drain: release order
      if (tid==0) fst(flags, selfF, t+1);
    }
  }
}

// ---- K4: classifier head over the fp32 target rows already in out ----------
__global__ __launch_bounds__(64) void k4_out(
    const void* __restrict__ wcls, const void* __restrict__ bcls,
    const int* __restrict__ wsmode, float* __restrict__ out){
  const int mode = wsmode[0];
  int b = blockIdx.x, lane = threadIdx.x;
  float a0=0.f, a1=0.f;
#pragma unroll
  for (int ch=0; ch<12; ++ch){
    int e = ch*64 + lane;
    float xv = out[256 + b*768 + e];
    a0 += xv * lds1(wcls, e, mode);
    a1 += xv * lds1(wcls, 768 + e, mode);
  }
#pragma unroll
  for (int off=32; off>0; off>>=1){
    a0 += __shfl_down(a0, off);
    a1 += __shfl_down(a1, off);
  }
  if (lane==0){
    float l0v = a0 + lds1(bcls, 0, mode);
    float l1v = a1 + lds1(bcls, 1, mode);
    out[b*2+0]     = l0v;                      // logits, fp32
    out[b*2+1]     = l1v;
    out[128+b*2+0] = sigf(l0v);                // probs, fp32
    out[128+b*2+1] = sigf(l1v);
  }
}

extern "C" void kernel_launch(void* const* d_in, const int* in_sizes, int n_in,
                              void* d_out, int out_size, void* d_ws, size_t ws_size,
                              hipStream_t stream){
  (void)in_sizes; (void)n_in; (void)out_size;
  const int* ctx  = (const int*)d_in[0];
  const int* pos  = (const int*)d_in[1];
  const void* emb = d_in[2];
  const void* wih = d_in[3];
  const void* whh = d_in[4];
  const void* blst= d_in[5];
  const void* wcls= d_in[6];
  const void* bcls= d_in[7];
  const int big = (ws_size >= (size_t)BIG_TOTAL) ? 1 : 0;
  const int xmask  = big ? 0x7FFFFFFF : 31;
  const int dslots = big ? 200 : 32;
  const long xpsz_u16 = 2L * dslots * XPSLOT;          // per layer (2 dirs)
  char* ws = (char*)d_ws;
  int* wsmode = (int*)ws;
  int* flags  = (int*)(ws + WS_FLAGS);
  u16* xstg   = (u16*)(ws + WS_XSTG);
  u16* xp0    = (u16*)(ws + WS_XP0);
  u16* xp1    = xp0 + xpsz_u16;
  u16* l0h    = xp1 + xpsz_u16;
  u16* l1h    = l0h + 201L*TSLOT;
  float* out  = (float*)d_out;
  hipLaunchKernelGGL(kdet, dim3(1), dim3(256), 0, stream,
                     (const unsigned int*)emb, wsmode);
  hipLaunchKernelGGL(k0_init, dim3(96), dim3(256), 0, stream,
                     (unsigned int*)l0h, (unsigned int*)l1h, flags);
  hipLaunchKernelGGL(kx, dim3(4800), dim3(256), 0, stream, emb, ctx, wsmode, xstg);
  hipLaunchKernelGGL(k3_lstm, dim3(128), dim3(256), 0, stream,
                     wih, whh, blst, pos, xstg, xp0, xp1, l0h, l1h, flags, wsmode,
                     out, big, xmask, dslots);
  hipLaunchKernelGGL(k4_out, dim3(64), dim3(64), 0, stream, wcls, bcls, wsmode, out);
}